// Round 2
// baseline (1224.912 us; speedup 1.0000x reference)
//
#include <hip/hip_runtime.h>

typedef __attribute__((ext_vector_type(8))) short bf16x8;
typedef __attribute__((ext_vector_type(4))) short bf16x4;
typedef __attribute__((ext_vector_type(4))) float f32x4;
typedef __attribute__((ext_vector_type(4))) int i32x4;
typedef __attribute__((ext_vector_type(4))) unsigned short us4;

#define N_HEAD 16
#define SEQ 2048

__device__ __forceinline__ unsigned short f2bf(float f) {
  union { float f; unsigned u; } v; v.f = f;
  unsigned r = v.u + 0x7fffu + ((v.u >> 16) & 1u);
  return (unsigned short)(r >> 16);
}

// ---------------- Kernel 0: f32 -> bf16 pre-convert (x and the 3 weights) ----
__global__ void conv_bf16(const float* __restrict__ x,
                          const float* __restrict__ wq,
                          const float* __restrict__ wk,
                          const float* __restrict__ wv,
                          unsigned short* __restrict__ xb,
                          unsigned short* __restrict__ wb)
{
  size_t i = ((size_t)blockIdx.x * 256 + threadIdx.x) * 8;
  const float* src;
  unsigned short* dst;
  size_t off;
  if (i < 4194304) { src = x; dst = xb; off = i; }
  else {
    size_t j = i - 4194304;
    int w = (int)(j >> 20);
    off = j & 1048575u;
    src = (w == 0) ? wq : (w == 1) ? wk : wv;
    dst = wb + ((size_t)w << 20);
  }
  float4 a = *(const float4*)(src + off);
  float4 b = *(const float4*)(src + off + 4);
  us4 u0 = { f2bf(a.x), f2bf(a.y), f2bf(a.z), f2bf(a.w) };
  us4 u1 = { f2bf(b.x), f2bf(b.y), f2bf(b.z), f2bf(b.w) };
  *(us4*)(dst + off) = u0;
  *(us4*)(dst + off + 4) = u1;
}

// ---------------- Kernel 1: fused QKV projection, bf16 inputs ---------------
// z=0: q (scaled 0.125) -> [b,h,s,d] bf16
// z=1: k                -> [b,h,s,d] bf16
// z=2: v                -> [b, feature(=h*64+d), s] bf16 (V^T for PV B-operand)
__global__ __launch_bounds__(256, 2)
void qkv_gemm_bf16(const unsigned short* __restrict__ xb,
                   const unsigned short* __restrict__ wb,
                   const float* __restrict__ bq, const float* __restrict__ bk,
                   const float* __restrict__ bv,
                   unsigned short* __restrict__ qws,
                   unsigned short* __restrict__ kws,
                   unsigned short* __restrict__ vtws)
{
  __shared__ unsigned short As[128 * 40];
  __shared__ unsigned short Bs[128 * 40];

  const int tid  = threadIdx.x;
  const int wave = tid >> 6, lane = tid & 63;
  const int quad = lane >> 4, lrow = lane & 15;
  const int wm = wave >> 1, wn = wave & 1;
  const int m0 = blockIdx.x * 128, n0 = blockIdx.y * 128;
  const int z = blockIdx.z;

  const unsigned short* W = wb + ((size_t)z << 20);
  const float* bvec = (z == 0) ? bq : (z == 1) ? bk : bv;

  f32x4 acc[4][4];
  #pragma unroll
  for (int mi = 0; mi < 4; ++mi)
    #pragma unroll
    for (int ni = 0; ni < 4; ++ni)
      acc[mi][ni] = (f32x4){0.f, 0.f, 0.f, 0.f};

  const int srow = tid >> 1, scol = (tid & 1) * 16;
  const unsigned short* xsrc = xb + (size_t)(m0 + srow) * 1024 + scol;
  const unsigned short* wsrc = W  + (size_t)(n0 + srow) * 1024 + scol;

  bf16x8 va0 = *(const bf16x8*)(xsrc);
  bf16x8 va1 = *(const bf16x8*)(xsrc + 8);
  bf16x8 vb0 = *(const bf16x8*)(wsrc);
  bf16x8 vb1 = *(const bf16x8*)(wsrc + 8);

  for (int k0 = 0; k0 < 1024; k0 += 32) {
    __syncthreads();
    *(bf16x8*)&As[srow * 40 + scol]     = va0;
    *(bf16x8*)&As[srow * 40 + scol + 8] = va1;
    *(bf16x8*)&Bs[srow * 40 + scol]     = vb0;
    *(bf16x8*)&Bs[srow * 40 + scol + 8] = vb1;
    __syncthreads();
    if (k0 < 992) {        // prefetch next k-tile while MFMAs run
      va0 = *(const bf16x8*)(xsrc + k0 + 32);
      va1 = *(const bf16x8*)(xsrc + k0 + 40);
      vb0 = *(const bf16x8*)(wsrc + k0 + 32);
      vb1 = *(const bf16x8*)(wsrc + k0 + 40);
    }
    bf16x8 a[4], b[4];
    #pragma unroll
    for (int mi = 0; mi < 4; ++mi)
      a[mi] = *(const bf16x8*)&As[(wm * 64 + mi * 16 + lrow) * 40 + quad * 8];
    #pragma unroll
    for (int ni = 0; ni < 4; ++ni)
      b[ni] = *(const bf16x8*)&Bs[(wn * 64 + ni * 16 + lrow) * 40 + quad * 8];
    #pragma unroll
    for (int mi = 0; mi < 4; ++mi)
      #pragma unroll
      for (int ni = 0; ni < 4; ++ni)
        acc[mi][ni] = __builtin_amdgcn_mfma_f32_16x16x32_bf16(a[mi], b[ni], acc[mi][ni], 0, 0, 0);
  }

  float badd[4];
  #pragma unroll
  for (int ni = 0; ni < 4; ++ni) badd[ni] = bvec[n0 + wn * 64 + ni * 16 + lrow];

  if (z == 2) {
    #pragma unroll
    for (int mi = 0; mi < 4; ++mi) {
      int i0 = m0 + wm * 64 + mi * 16 + quad * 4;
      int bb = i0 >> 11, ss0 = i0 & 2047;
      #pragma unroll
      for (int ni = 0; ni < 4; ++ni) {
        int j = n0 + wn * 64 + ni * 16 + lrow;     // feature = h*64+d
        us4 u = { f2bf(acc[mi][ni][0] + badd[ni]),
                  f2bf(acc[mi][ni][1] + badd[ni]),
                  f2bf(acc[mi][ni][2] + badd[ni]),
                  f2bf(acc[mi][ni][3] + badd[ni]) };
        *(us4*)(vtws + ((size_t)(bb * 1024 + j)) * 2048 + ss0) = u;
      }
    }
  } else {
    #pragma unroll
    for (int mi = 0; mi < 4; ++mi) {
      #pragma unroll
      for (int ni = 0; ni < 4; ++ni) {
        int j = n0 + wn * 64 + ni * 16 + lrow;
        int hh = j >> 6, dd = j & 63;
        #pragma unroll
        for (int r = 0; r < 4; ++r) {
          int i = m0 + wm * 64 + mi * 16 + quad * 4 + r;
          int bb = i >> 11, ss = i & 2047;
          float y = acc[mi][ni][r] + badd[ni];
          if (z == 0)
            qws[(((size_t)(bb * 16 + hh)) * 2048 + ss) * 64 + dd] = f2bf(y * 0.125f);
          else
            kws[(((size_t)(bb * 16 + hh)) * 2048 + ss) * 64 + dd] = f2bf(y);
        }
      }
    }
  }
}

// ---------------- Kernel 2: fused attention, swapped-operand + K=16 PV ------
// Block = (bh, 16-q-row strip), 512 threads = 8 waves; wave owns 256 cols.
// QK^T via mfma(K,Q): lane(quad,lrow) holds P[q=lrow][col=cb+t*16+quad*4+r].
// That IS the A-fragment of 16x16x16 MFMA (A[m=lrow][k=quad*4+j]) -> PV needs
// NO data movement: pack S[t] to bf16x4 and MFMA directly (zero-shuffle PV).
// blockIdx.x swizzled so the b=0/b=1 blocks sharing bias rows sit on the same
// XCD (linear ids differ by 8).
__global__ __launch_bounds__(512, 4)
void attn2(const unsigned short* __restrict__ qws,
           const unsigned short* __restrict__ kws,
           const unsigned short* __restrict__ vtws,
           const float* __restrict__ bias,
           const int* __restrict__ mask,
           float* __restrict__ out)
{
  const int tid  = threadIdx.x;
  const int wave = tid >> 6, lane = tid & 63;
  const int quad = lane >> 4, lrow = lane & 15;
  const int bx = blockIdx.x;                 // 0..31
  const int h  = (bx & 7) | (((bx >> 4) & 1) << 3);
  const int bb = (bx >> 3) & 1;              // bx and bx+8: same h, same XCD
  const int bh = bb * 16 + h;
  const int q0 = blockIdx.y * 16;
  const int cb = wave * 256;

  const unsigned short* qh  = qws  + (size_t)bh * SEQ * 64;
  const unsigned short* kh  = kws  + (size_t)bh * SEQ * 64;
  const unsigned short* vth = vtws + (size_t)bh * 64 * SEQ;
  float* out_o = out;
  float* out_w = out + (size_t)2 * N_HEAD * SEQ * 64;

  __shared__ float red[8][16];
  __shared__ float obuf[8][16][68];            // cross-wave PV reduce (+4 pad)
#if !__has_builtin(__builtin_amdgcn_mfma_f32_16x16x16bf16_1k)
  __shared__ unsigned short pbuf[8][16][40];   // fallback bounce buffer
#endif

  // Q fragment (B-operand of swapped QK^T): lane -> Q[q=lrow][k=quad*8+j]
  bf16x8 aq[2];
  #pragma unroll
  for (int ks = 0; ks < 2; ++ks)
    aq[ks] = *(const bf16x8*)(qh + (size_t)(q0 + lrow) * 64 + ks * 32 + quad * 8);

  const unsigned short* kp = kh + (size_t)(cb + lrow) * 64 + quad * 8;
  const float* bp = bias + ((size_t)h * SEQ + q0 + lrow) * SEQ + cb + quad * 4;
  const int*   mp = mask + (size_t)(q0 + lrow) * SEQ + cb + quad * 4;

  const float L2E = 1.44269504f;
  f32x4 S[16];          // e-values: lane&15 = q-row, cols = cb + t*16 + quad*4 + r
  float rsum = 0.f;

  #pragma unroll
  for (int t = 0; t < 16; ++t) {
    bf16x8 k0f = *(const bf16x8*)(kp + t * 1024);        // k-rows, d 0..31
    bf16x8 k1f = *(const bf16x8*)(kp + t * 1024 + 32);   // d 32..63
    f32x4 c = (f32x4){0.f, 0.f, 0.f, 0.f};
    c = __builtin_amdgcn_mfma_f32_16x16x32_bf16(k0f, aq[0], c, 0, 0, 0);
    c = __builtin_amdgcn_mfma_f32_16x16x32_bf16(k1f, aq[1], c, 0, 0, 0);
    f32x4 bbv = *(const f32x4*)(bp + t * 16);
    i32x4 mmv = *(const i32x4*)(mp + t * 16);
    #pragma unroll
    for (int r = 0; r < 4; ++r) {
      float e = (mmv[r] == 0) ? 0.f : exp2f((c[r] + bbv[r]) * L2E);
      S[t][r] = e;
      rsum += e;
    }
  }

  // row sum: quads of same q-row, then cross-wave via LDS
  rsum += __shfl_xor(rsum, 16);
  rsum += __shfl_xor(rsum, 32);
  if (lane < 16) red[wave][lrow] = rsum;
  __syncthreads();
  float tot = 0.f;
  #pragma unroll
  for (int w = 0; w < 8; ++w) tot += red[w][lrow];
  const float inv = 1.0f / tot;

  f32x4 O[4];
  #pragma unroll
  for (int n = 0; n < 4; ++n) O[n] = (f32x4){0.f, 0.f, 0.f, 0.f};

  float* wbase = out_w + ((size_t)bh * SEQ + q0 + lrow) * SEQ + cb + quad * 4;

#if __has_builtin(__builtin_amdgcn_mfma_f32_16x16x16bf16_1k)
  // ---- zero-shuffle PV: 16-col windows, K=16 MFMA, A-frag = S in place
  const unsigned short* vp = vth + (size_t)lrow * SEQ + cb + quad * 4;
  #pragma unroll
  for (int t = 0; t < 16; ++t) {
    f32x4 wv;
    #pragma unroll
    for (int r = 0; r < 4; ++r) wv[r] = S[t][r] * inv;
#if __has_builtin(__builtin_nontemporal_store)
    __builtin_nontemporal_store(wv, (f32x4*)(wbase + t * 16));
#else
    *(f32x4*)(wbase + t * 16) = wv;
#endif
    bf16x4 a4 = { (short)f2bf(wv[0]), (short)f2bf(wv[1]),
                  (short)f2bf(wv[2]), (short)f2bf(wv[3]) };
    #pragma unroll
    for (int n = 0; n < 4; ++n) {
      bf16x4 v4 = *(const bf16x4*)(vp + (size_t)n * 16 * SEQ + t * 16);
      O[n] = __builtin_amdgcn_mfma_f32_16x16x16bf16_1k(a4, v4, O[n], 0, 0, 0);
    }
  }
#else
  // ---- fallback: LDS bounce per 32-col window (round-1 path)
  const unsigned short* vp = vth + (size_t)lrow * SEQ + cb + quad * 8;
  #pragma unroll
  for (int cc = 0; cc < 8; ++cc) {
    #pragma unroll
    for (int tt = 0; tt < 2; ++tt) {
      const int t = cc * 2 + tt;
      f32x4 wv;
      #pragma unroll
      for (int r = 0; r < 4; ++r) wv[r] = S[t][r] * inv;
      *(f32x4*)(wbase + t * 16) = wv;
      us4 u = { f2bf(wv[0]), f2bf(wv[1]), f2bf(wv[2]), f2bf(wv[3]) };
      *(us4*)&pbuf[wave][lrow][tt * 16 + quad * 4] = u;
    }
    asm volatile("s_waitcnt lgkmcnt(0)" ::: "memory");
    bf16x8 aw = *(const bf16x8*)&pbuf[wave][lrow][quad * 8];
    #pragma unroll
    for (int n = 0; n < 4; ++n) {
      bf16x8 v8 = *(const bf16x8*)(vp + (size_t)n * 16 * SEQ + cc * 32);
      O[n] = __builtin_amdgcn_mfma_f32_16x16x32_bf16(aw, v8, O[n], 0, 0, 0);
    }
  }
#endif

  // cross-wave reduce of O, write first output
  #pragma unroll
  for (int n = 0; n < 4; ++n)
    #pragma unroll
    for (int r = 0; r < 4; ++r)
      obuf[wave][quad * 4 + r][n * 16 + lrow] = O[n][r];
  __syncthreads();
  #pragma unroll
  for (int e = 0; e < 2; ++e) {
    int idx = e * 512 + tid;
    int row = idx >> 6, dd = idx & 63;
    float v = 0.f;
    #pragma unroll
    for (int w = 0; w < 8; ++w) v += obuf[w][row][dd];
    out_o[((size_t)bh * SEQ + q0 + row) * 64 + dd] = v;
  }
}

extern "C" void kernel_launch(void* const* d_in, const int* in_sizes, int n_in,
                              void* d_out, int out_size, void* d_ws, size_t ws_size,
                              hipStream_t stream) {
  const float* x    = (const float*)d_in[0];
  const float* bias = (const float*)d_in[1];
  const int*   mask = (const int*)d_in[2];
  const float* wq   = (const float*)d_in[3];
  const float* bq   = (const float*)d_in[4];
  const float* wk   = (const float*)d_in[5];
  const float* bk   = (const float*)d_in[6];
  const float* wv   = (const float*)d_in[7];
  const float* bv   = (const float*)d_in[8];

  unsigned short* qws  = (unsigned short*)d_ws;           // 8 MB
  unsigned short* kws  = qws + (size_t)4194304;           // 8 MB
  unsigned short* vtws = kws + (size_t)4194304;           // 8 MB (V^T)
  float* out = (float*)d_out;

  // bf16 staging scratch (14 MB): prefer ws if it fits, else tail of d_out.
  // d_out tail is safe: conv/qkv read it strictly BEFORE attn2 overwrites
  // out_w (stream-ordered), and attn2 rewrites every byte afterwards.
  unsigned short* xb;
  if (ws_size >= (size_t)39845888) {
    xb = vtws + (size_t)4194304;
  } else {
    xb = (unsigned short*)((char*)d_out + ((size_t)out_size - (size_t)14 * 1024 * 1024));
  }
  unsigned short* wb = xb + (size_t)4194304;

  conv_bf16<<<dim3(3584), 256, 0, stream>>>(x, wq, wk, wv, xb, wb);
  qkv_gemm_bf16<<<dim3(32, 8, 3), 256, 0, stream>>>(xb, wb, bq, bk, bv,
                                                    qws, kws, vtws);
  // grid: x = swizzled bh (bias-sharing pairs 8 apart -> same XCD), y = strips
  attn2<<<dim3(32, 128), 512, 0, stream>>>(qws, kws, vtws, bias, mask, out);
}

// Round 3
// 1170.152 us; speedup vs baseline: 1.0468x; 1.0468x over previous
//
#include <hip/hip_runtime.h>

typedef __attribute__((ext_vector_type(8))) short bf16x8;
typedef __attribute__((ext_vector_type(4))) short bf16x4;
typedef __attribute__((ext_vector_type(4))) float f32x4;
typedef __attribute__((ext_vector_type(4))) int i32x4;
typedef __attribute__((ext_vector_type(4))) unsigned short us4;

#define N_HEAD 16
#define SEQ 2048

__device__ __forceinline__ unsigned short f2bf(float f) {
  union { float f; unsigned u; } v; v.f = f;
  unsigned r = v.u + 0x7fffu + ((v.u >> 16) & 1u);
  return (unsigned short)(r >> 16);
}

// ---------------- Kernel 0: f32 -> bf16 pre-convert (x and the 3 weights) ----
__global__ void conv_bf16(const float* __restrict__ x,
                          const float* __restrict__ wq,
                          const float* __restrict__ wk,
                          const float* __restrict__ wv,
                          unsigned short* __restrict__ xb,
                          unsigned short* __restrict__ wb)
{
  size_t i = ((size_t)blockIdx.x * 256 + threadIdx.x) * 8;
  const float* src;
  unsigned short* dst;
  size_t off;
  if (i < 4194304) { src = x; dst = xb; off = i; }
  else {
    size_t j = i - 4194304;
    int w = (int)(j >> 20);
    off = j & 1048575u;
    src = (w == 0) ? wq : (w == 1) ? wk : wv;
    dst = wb + ((size_t)w << 20);
  }
  float4 a = *(const float4*)(src + off);
  float4 b = *(const float4*)(src + off + 4);
  us4 u0 = { f2bf(a.x), f2bf(a.y), f2bf(a.z), f2bf(a.w) };
  us4 u1 = { f2bf(b.x), f2bf(b.y), f2bf(b.z), f2bf(b.w) };
  *(us4*)(dst + off) = u0;
  *(us4*)(dst + off + 4) = u1;
}

// ---------------- Kernel 1: fused QKV projection, bf16 inputs ---------------
// z=0: q (scaled 0.125) -> [b,h,s,d] bf16
// z=1: k                -> [b,h,s,d] bf16
// z=2: v                -> [b, feature(=h*64+d), s] bf16 (V^T for PV B-operand)
// NOTE: deliberately unchanged from round 2 (diagnostic round for qkv timing).
__global__ __launch_bounds__(256, 2)
void qkv_gemm_bf16(const unsigned short* __restrict__ xb,
                   const unsigned short* __restrict__ wb,
                   const float* __restrict__ bq, const float* __restrict__ bk,
                   const float* __restrict__ bv,
                   unsigned short* __restrict__ qws,
                   unsigned short* __restrict__ kws,
                   unsigned short* __restrict__ vtws)
{
  __shared__ unsigned short As[128 * 40];
  __shared__ unsigned short Bs[128 * 40];

  const int tid  = threadIdx.x;
  const int wave = tid >> 6, lane = tid & 63;
  const int quad = lane >> 4, lrow = lane & 15;
  const int wm = wave >> 1, wn = wave & 1;
  const int m0 = blockIdx.x * 128, n0 = blockIdx.y * 128;
  const int z = blockIdx.z;

  const unsigned short* W = wb + ((size_t)z << 20);
  const float* bvec = (z == 0) ? bq : (z == 1) ? bk : bv;

  f32x4 acc[4][4];
  #pragma unroll
  for (int mi = 0; mi < 4; ++mi)
    #pragma unroll
    for (int ni = 0; ni < 4; ++ni)
      acc[mi][ni] = (f32x4){0.f, 0.f, 0.f, 0.f};

  const int srow = tid >> 1, scol = (tid & 1) * 16;
  const unsigned short* xsrc = xb + (size_t)(m0 + srow) * 1024 + scol;
  const unsigned short* wsrc = W  + (size_t)(n0 + srow) * 1024 + scol;

  bf16x8 va0 = *(const bf16x8*)(xsrc);
  bf16x8 va1 = *(const bf16x8*)(xsrc + 8);
  bf16x8 vb0 = *(const bf16x8*)(wsrc);
  bf16x8 vb1 = *(const bf16x8*)(wsrc + 8);

  for (int k0 = 0; k0 < 1024; k0 += 32) {
    __syncthreads();
    *(bf16x8*)&As[srow * 40 + scol]     = va0;
    *(bf16x8*)&As[srow * 40 + scol + 8] = va1;
    *(bf16x8*)&Bs[srow * 40 + scol]     = vb0;
    *(bf16x8*)&Bs[srow * 40 + scol + 8] = vb1;
    __syncthreads();
    if (k0 < 992) {        // prefetch next k-tile while MFMAs run
      va0 = *(const bf16x8*)(xsrc + k0 + 32);
      va1 = *(const bf16x8*)(xsrc + k0 + 40);
      vb0 = *(const bf16x8*)(wsrc + k0 + 32);
      vb1 = *(const bf16x8*)(wsrc + k0 + 40);
    }
    bf16x8 a[4], b[4];
    #pragma unroll
    for (int mi = 0; mi < 4; ++mi)
      a[mi] = *(const bf16x8*)&As[(wm * 64 + mi * 16 + lrow) * 40 + quad * 8];
    #pragma unroll
    for (int ni = 0; ni < 4; ++ni)
      b[ni] = *(const bf16x8*)&Bs[(wn * 64 + ni * 16 + lrow) * 40 + quad * 8];
    #pragma unroll
    for (int mi = 0; mi < 4; ++mi)
      #pragma unroll
      for (int ni = 0; ni < 4; ++ni)
        acc[mi][ni] = __builtin_amdgcn_mfma_f32_16x16x32_bf16(a[mi], b[ni], acc[mi][ni], 0, 0, 0);
  }

  float badd[4];
  #pragma unroll
  for (int ni = 0; ni < 4; ++ni) badd[ni] = bvec[n0 + wn * 64 + ni * 16 + lrow];

  if (z == 2) {
    #pragma unroll
    for (int mi = 0; mi < 4; ++mi) {
      int i0 = m0 + wm * 64 + mi * 16 + quad * 4;
      int bb = i0 >> 11, ss0 = i0 & 2047;
      #pragma unroll
      for (int ni = 0; ni < 4; ++ni) {
        int j = n0 + wn * 64 + ni * 16 + lrow;     // feature = h*64+d
        us4 u = { f2bf(acc[mi][ni][0] + badd[ni]),
                  f2bf(acc[mi][ni][1] + badd[ni]),
                  f2bf(acc[mi][ni][2] + badd[ni]),
                  f2bf(acc[mi][ni][3] + badd[ni]) };
        *(us4*)(vtws + ((size_t)(bb * 1024 + j)) * 2048 + ss0) = u;
      }
    }
  } else {
    #pragma unroll
    for (int mi = 0; mi < 4; ++mi) {
      #pragma unroll
      for (int ni = 0; ni < 4; ++ni) {
        int j = n0 + wn * 64 + ni * 16 + lrow;
        int hh = j >> 6, dd = j & 63;
        #pragma unroll
        for (int r = 0; r < 4; ++r) {
          int i = m0 + wm * 64 + mi * 16 + quad * 4 + r;
          int bb = i >> 11, ss = i & 2047;
          float y = acc[mi][ni][r] + badd[ni];
          if (z == 0)
            qws[(((size_t)(bb * 16 + hh)) * 2048 + ss) * 64 + dd] = f2bf(y * 0.125f);
          else
            kws[(((size_t)(bb * 16 + hh)) * 2048 + ss) * 64 + dd] = f2bf(y);
        }
      }
    }
  }
}

// ---------------- Kernel 2: fused attention, swapped-operand + K=16 PV ------
// Block = (bh, 16-q-row strip), 512 threads = 8 waves; wave owns 256 cols.
// QK^T via mfma(K,Q): lane(quad,lrow) holds P[q=lrow][col=cb+t*16+quad*4+r].
// That IS the A-fragment of 16x16x16 MFMA -> zero-shuffle PV.
// Round-3 change vs round-2: nontemporal weight store REMOVED (it caused
// +223 MB HBM write amplification and the 482->638 regression); s_setprio(1)
// added around MFMA clusters (T5).
__global__ __launch_bounds__(512, 4)
void attn2(const unsigned short* __restrict__ qws,
           const unsigned short* __restrict__ kws,
           const unsigned short* __restrict__ vtws,
           const float* __restrict__ bias,
           const int* __restrict__ mask,
           float* __restrict__ out)
{
  const int tid  = threadIdx.x;
  const int wave = tid >> 6, lane = tid & 63;
  const int quad = lane >> 4, lrow = lane & 15;
  const int bx = blockIdx.x;                 // 0..31
  const int h  = (bx & 7) | (((bx >> 4) & 1) << 3);
  const int bb = (bx >> 3) & 1;              // bx and bx+8: same h, same XCD
  const int bh = bb * 16 + h;
  const int q0 = blockIdx.y * 16;
  const int cb = wave * 256;

  const unsigned short* qh  = qws  + (size_t)bh * SEQ * 64;
  const unsigned short* kh  = kws  + (size_t)bh * SEQ * 64;
  const unsigned short* vth = vtws + (size_t)bh * 64 * SEQ;
  float* out_o = out;
  float* out_w = out + (size_t)2 * N_HEAD * SEQ * 64;

  __shared__ float red[8][16];
  __shared__ float obuf[8][16][68];            // cross-wave PV reduce (+4 pad)
#if !__has_builtin(__builtin_amdgcn_mfma_f32_16x16x16bf16_1k)
  __shared__ unsigned short pbuf[8][16][40];   // fallback bounce buffer
#endif

  // Q fragment (B-operand of swapped QK^T): lane -> Q[q=lrow][k=quad*8+j]
  bf16x8 aq[2];
  #pragma unroll
  for (int ks = 0; ks < 2; ++ks)
    aq[ks] = *(const bf16x8*)(qh + (size_t)(q0 + lrow) * 64 + ks * 32 + quad * 8);

  const unsigned short* kp = kh + (size_t)(cb + lrow) * 64 + quad * 8;
  const float* bp = bias + ((size_t)h * SEQ + q0 + lrow) * SEQ + cb + quad * 4;
  const int*   mp = mask + (size_t)(q0 + lrow) * SEQ + cb + quad * 4;

  const float L2E = 1.44269504f;
  f32x4 S[16];          // e-values: lane&15 = q-row, cols = cb + t*16 + quad*4 + r
  float rsum = 0.f;

  #pragma unroll
  for (int t = 0; t < 16; ++t) {
    bf16x8 k0f = *(const bf16x8*)(kp + t * 1024);        // k-rows, d 0..31
    bf16x8 k1f = *(const bf16x8*)(kp + t * 1024 + 32);   // d 32..63
    f32x4 c = (f32x4){0.f, 0.f, 0.f, 0.f};
    __builtin_amdgcn_s_setprio(1);
    c = __builtin_amdgcn_mfma_f32_16x16x32_bf16(k0f, aq[0], c, 0, 0, 0);
    c = __builtin_amdgcn_mfma_f32_16x16x32_bf16(k1f, aq[1], c, 0, 0, 0);
    __builtin_amdgcn_s_setprio(0);
    f32x4 bbv = *(const f32x4*)(bp + t * 16);
    i32x4 mmv = *(const i32x4*)(mp + t * 16);
    #pragma unroll
    for (int r = 0; r < 4; ++r) {
      float e = (mmv[r] == 0) ? 0.f : exp2f((c[r] + bbv[r]) * L2E);
      S[t][r] = e;
      rsum += e;
    }
  }

  // row sum: quads of same q-row, then cross-wave via LDS
  rsum += __shfl_xor(rsum, 16);
  rsum += __shfl_xor(rsum, 32);
  if (lane < 16) red[wave][lrow] = rsum;
  __syncthreads();
  float tot = 0.f;
  #pragma unroll
  for (int w = 0; w < 8; ++w) tot += red[w][lrow];
  const float inv = 1.0f / tot;

  f32x4 O[4];
  #pragma unroll
  for (int n = 0; n < 4; ++n) O[n] = (f32x4){0.f, 0.f, 0.f, 0.f};

  float* wbase = out_w + ((size_t)bh * SEQ + q0 + lrow) * SEQ + cb + quad * 4;

#if __has_builtin(__builtin_amdgcn_mfma_f32_16x16x16bf16_1k)
  // ---- zero-shuffle PV: 16-col windows, K=16 MFMA, A-frag = S in place
  const unsigned short* vp = vth + (size_t)lrow * SEQ + cb + quad * 4;
  #pragma unroll
  for (int t = 0; t < 16; ++t) {
    f32x4 wv;
    #pragma unroll
    for (int r = 0; r < 4; ++r) wv[r] = S[t][r] * inv;
    *(f32x4*)(wbase + t * 16) = wv;          // plain store (nt REMOVED)
    bf16x4 a4 = { (short)f2bf(wv[0]), (short)f2bf(wv[1]),
                  (short)f2bf(wv[2]), (short)f2bf(wv[3]) };
    __builtin_amdgcn_s_setprio(1);
    #pragma unroll
    for (int n = 0; n < 4; ++n) {
      bf16x4 v4 = *(const bf16x4*)(vp + (size_t)n * 16 * SEQ + t * 16);
      O[n] = __builtin_amdgcn_mfma_f32_16x16x16bf16_1k(a4, v4, O[n], 0, 0, 0);
    }
    __builtin_amdgcn_s_setprio(0);
  }
#else
  // ---- fallback: LDS bounce per 32-col window (round-1 path)
  const unsigned short* vp = vth + (size_t)lrow * SEQ + cb + quad * 8;
  #pragma unroll
  for (int cc = 0; cc < 8; ++cc) {
    #pragma unroll
    for (int tt = 0; tt < 2; ++tt) {
      const int t = cc * 2 + tt;
      f32x4 wv;
      #pragma unroll
      for (int r = 0; r < 4; ++r) wv[r] = S[t][r] * inv;
      *(f32x4*)(wbase + t * 16) = wv;
      us4 u = { f2bf(wv[0]), f2bf(wv[1]), f2bf(wv[2]), f2bf(wv[3]) };
      *(us4*)&pbuf[wave][lrow][tt * 16 + quad * 4] = u;
    }
    asm volatile("s_waitcnt lgkmcnt(0)" ::: "memory");
    bf16x8 aw = *(const bf16x8*)&pbuf[wave][lrow][quad * 8];
    #pragma unroll
    for (int n = 0; n < 4; ++n) {
      bf16x8 v8 = *(const bf16x8*)(vp + (size_t)n * 16 * SEQ + cc * 32);
      O[n] = __builtin_amdgcn_mfma_f32_16x16x32_bf16(aw, v8, O[n], 0, 0, 0);
    }
  }
#endif

  // cross-wave reduce of O, write first output
  #pragma unroll
  for (int n = 0; n < 4; ++n)
    #pragma unroll
    for (int r = 0; r < 4; ++r)
      obuf[wave][quad * 4 + r][n * 16 + lrow] = O[n][r];
  __syncthreads();
  #pragma unroll
  for (int e = 0; e < 2; ++e) {
    int idx = e * 512 + tid;
    int row = idx >> 6, dd = idx & 63;
    float v = 0.f;
    #pragma unroll
    for (int w = 0; w < 8; ++w) v += obuf[w][row][dd];
    out_o[((size_t)bh * SEQ + q0 + row) * 64 + dd] = v;
  }
}

extern "C" void kernel_launch(void* const* d_in, const int* in_sizes, int n_in,
                              void* d_out, int out_size, void* d_ws, size_t ws_size,
                              hipStream_t stream) {
  const float* x    = (const float*)d_in[0];
  const float* bias = (const float*)d_in[1];
  const int*   mask = (const int*)d_in[2];
  const float* wq   = (const float*)d_in[3];
  const float* bq   = (const float*)d_in[4];
  const float* wk   = (const float*)d_in[5];
  const float* bk   = (const float*)d_in[6];
  const float* wv   = (const float*)d_in[7];
  const float* bv   = (const float*)d_in[8];

  unsigned short* qws  = (unsigned short*)d_ws;           // 8 MB
  unsigned short* kws  = qws + (size_t)4194304;           // 8 MB
  unsigned short* vtws = kws + (size_t)4194304;           // 8 MB (V^T)
  float* out = (float*)d_out;

  // bf16 staging scratch (14 MB): prefer ws if it fits, else tail of d_out.
  // d_out tail is safe: conv/qkv read it strictly BEFORE attn2 overwrites
  // out_w (stream-ordered), and attn2 rewrites every byte afterwards.
  unsigned short* xb;
  if (ws_size >= (size_t)39845888) {
    xb = vtws + (size_t)4194304;
  } else {
    xb = (unsigned short*)((char*)d_out + ((size_t)out_size - (size_t)14 * 1024 * 1024));
  }
  unsigned short* wb = xb + (size_t)4194304;

  conv_bf16<<<dim3(3584), 256, 0, stream>>>(x, wq, wk, wv, xb, wb);
  qkv_gemm_bf16<<<dim3(32, 8, 3), 256, 0, stream>>>(xb, wb, bq, bk, bv,
                                                    qws, kws, vtws);
  // grid: x = swizzled bh (bias-sharing pairs 8 apart -> same XCD), y = strips
  attn2<<<dim3(32, 128), 512, 0, stream>>>(qws, kws, vtws, bias, mask, out);
}

// Round 4
// 1054.255 us; speedup vs baseline: 1.1619x; 1.1099x over previous
//
#include <hip/hip_runtime.h>

typedef __attribute__((ext_vector_type(8))) short bf16x8;
typedef __attribute__((ext_vector_type(4))) float f32x4;
typedef __attribute__((ext_vector_type(4))) int i32x4;
typedef __attribute__((ext_vector_type(4))) unsigned short us4;

#define N_HEAD 16
#define SEQ 2048

__device__ __forceinline__ unsigned short f2bf(float f) {
  union { float f; unsigned u; } v; v.f = f;
  unsigned r = v.u + 0x7fffu + ((v.u >> 16) & 1u);
  return (unsigned short)(r >> 16);
}

__device__ __forceinline__ float b2f(unsigned short u) {
  union { float f; unsigned u; } v; v.u = (unsigned)u << 16;
  return v.f;
}

// ---------------- Kernel 0: f32 -> bf16 pre-convert (x and the 3 weights) ----
__global__ void conv_bf16(const float* __restrict__ x,
                          const float* __restrict__ wq,
                          const float* __restrict__ wk,
                          const float* __restrict__ wv,
                          unsigned short* __restrict__ xb,
                          unsigned short* __restrict__ wb)
{
  size_t i = ((size_t)blockIdx.x * 256 + threadIdx.x) * 8;
  const float* src;
  unsigned short* dst;
  size_t off;
  if (i < 4194304) { src = x; dst = xb; off = i; }
  else {
    size_t j = i - 4194304;
    int w = (int)(j >> 20);
    off = j & 1048575u;
    src = (w == 0) ? wq : (w == 1) ? wk : wv;
    dst = wb + ((size_t)w << 20);
  }
  float4 a = *(const float4*)(src + off);
  float4 b = *(const float4*)(src + off + 4);
  us4 u0 = { f2bf(a.x), f2bf(a.y), f2bf(a.z), f2bf(a.w) };
  us4 u1 = { f2bf(b.x), f2bf(b.y), f2bf(b.z), f2bf(b.w) };
  *(us4*)(dst + off) = u0;
  *(us4*)(dst + off + 4) = u1;
}

// ---------------- Kernel 1: fused QKV projection, bf16 inputs ---------------
// z=0: q (scaled 0.125) -> [b,h,s,d] bf16
// z=1: k                -> [b,h,s,d] bf16
// z=2: v                -> [b, feature(=h*64+d), s] bf16 (V^T for PV B-operand)
__global__ __launch_bounds__(256, 2)
void qkv_gemm_bf16(const unsigned short* __restrict__ xb,
                   const unsigned short* __restrict__ wb,
                   const float* __restrict__ bq, const float* __restrict__ bk,
                   const float* __restrict__ bv,
                   unsigned short* __restrict__ qws,
                   unsigned short* __restrict__ kws,
                   unsigned short* __restrict__ vtws)
{
  __shared__ unsigned short As[128 * 40];
  __shared__ unsigned short Bs[128 * 40];

  const int tid  = threadIdx.x;
  const int wave = tid >> 6, lane = tid & 63;
  const int quad = lane >> 4, lrow = lane & 15;
  const int wm = wave >> 1, wn = wave & 1;
  const int m0 = blockIdx.x * 128, n0 = blockIdx.y * 128;
  const int z = blockIdx.z;

  const unsigned short* W = wb + ((size_t)z << 20);
  const float* bvec = (z == 0) ? bq : (z == 1) ? bk : bv;

  f32x4 acc[4][4];
  #pragma unroll
  for (int mi = 0; mi < 4; ++mi)
    #pragma unroll
    for (int ni = 0; ni < 4; ++ni)
      acc[mi][ni] = (f32x4){0.f, 0.f, 0.f, 0.f};

  const int srow = tid >> 1, scol = (tid & 1) * 16;
  const unsigned short* xsrc = xb + (size_t)(m0 + srow) * 1024 + scol;
  const unsigned short* wsrc = W  + (size_t)(n0 + srow) * 1024 + scol;

  bf16x8 va0 = *(const bf16x8*)(xsrc);
  bf16x8 va1 = *(const bf16x8*)(xsrc + 8);
  bf16x8 vb0 = *(const bf16x8*)(wsrc);
  bf16x8 vb1 = *(const bf16x8*)(wsrc + 8);

  for (int k0 = 0; k0 < 1024; k0 += 32) {
    __syncthreads();
    *(bf16x8*)&As[srow * 40 + scol]     = va0;
    *(bf16x8*)&As[srow * 40 + scol + 8] = va1;
    *(bf16x8*)&Bs[srow * 40 + scol]     = vb0;
    *(bf16x8*)&Bs[srow * 40 + scol + 8] = vb1;
    __syncthreads();
    if (k0 < 992) {        // prefetch next k-tile while MFMAs run
      va0 = *(const bf16x8*)(xsrc + k0 + 32);
      va1 = *(const bf16x8*)(xsrc + k0 + 40);
      vb0 = *(const bf16x8*)(wsrc + k0 + 32);
      vb1 = *(const bf16x8*)(wsrc + k0 + 40);
    }
    bf16x8 a[4], b[4];
    #pragma unroll
    for (int mi = 0; mi < 4; ++mi)
      a[mi] = *(const bf16x8*)&As[(wm * 64 + mi * 16 + lrow) * 40 + quad * 8];
    #pragma unroll
    for (int ni = 0; ni < 4; ++ni)
      b[ni] = *(const bf16x8*)&Bs[(wn * 64 + ni * 16 + lrow) * 40 + quad * 8];
    #pragma unroll
    for (int mi = 0; mi < 4; ++mi)
      #pragma unroll
      for (int ni = 0; ni < 4; ++ni)
        acc[mi][ni] = __builtin_amdgcn_mfma_f32_16x16x32_bf16(a[mi], b[ni], acc[mi][ni], 0, 0, 0);
  }

  float badd[4];
  #pragma unroll
  for (int ni = 0; ni < 4; ++ni) badd[ni] = bvec[n0 + wn * 64 + ni * 16 + lrow];

  if (z == 2) {
    #pragma unroll
    for (int mi = 0; mi < 4; ++mi) {
      int i0 = m0 + wm * 64 + mi * 16 + quad * 4;
      int bb = i0 >> 11, ss0 = i0 & 2047;
      #pragma unroll
      for (int ni = 0; ni < 4; ++ni) {
        int j = n0 + wn * 64 + ni * 16 + lrow;     // feature = h*64+d
        us4 u = { f2bf(acc[mi][ni][0] + badd[ni]),
                  f2bf(acc[mi][ni][1] + badd[ni]),
                  f2bf(acc[mi][ni][2] + badd[ni]),
                  f2bf(acc[mi][ni][3] + badd[ni]) };
        *(us4*)(vtws + ((size_t)(bb * 1024 + j)) * 2048 + ss0) = u;
      }
    }
  } else {
    #pragma unroll
    for (int mi = 0; mi < 4; ++mi) {
      #pragma unroll
      for (int ni = 0; ni < 4; ++ni) {
        int j = n0 + wn * 64 + ni * 16 + lrow;
        int hh = j >> 6, dd = j & 63;
        #pragma unroll
        for (int r = 0; r < 4; ++r) {
          int i = m0 + wm * 64 + mi * 16 + quad * 4 + r;
          int bb = i >> 11, ss = i & 2047;
          float y = acc[mi][ni][r] + badd[ni];
          if (z == 0)
            qws[(((size_t)(bb * 16 + hh)) * 2048 + ss) * 64 + dd] = f2bf(y * 0.125f);
          else
            kws[(((size_t)(bb * 16 + hh)) * 2048 + ss) * 64 + dd] = f2bf(y);
        }
      }
    }
  }
}

// ---------------- Kernel 2: fused attention ---------------------------------
// Round-4: PV reverted to the MEASURED-fastest round-1 LDS-bounce K=32 form
// (K=16 zero-shuffle PV regressed 100us in rounds 2/3). Kept from rounds 2/3:
// XCD bh-pair swizzle (FETCH 473->300 MB). New: S held as bf16 (us4, 32 regs
// instead of 64) converted in the QK loop; PV consumes UNNORMALIZED bf16(e)
// and O is normalized in the epilogue (O = (sum e*V)/sum e). Weight output
// w = f32(bf16(e))*inv: added err <= 2^-9 * max_w ~ 4e-5, well under tol.
__global__ __launch_bounds__(512, 4)
void attn2(const unsigned short* __restrict__ qws,
           const unsigned short* __restrict__ kws,
           const unsigned short* __restrict__ vtws,
           const float* __restrict__ bias,
           const int* __restrict__ mask,
           float* __restrict__ out)
{
  const int tid  = threadIdx.x;
  const int wave = tid >> 6, lane = tid & 63;
  const int quad = lane >> 4, lrow = lane & 15;
  const int bx = blockIdx.x;                 // 0..31
  const int h  = (bx & 7) | (((bx >> 4) & 1) << 3);
  const int bb = (bx >> 3) & 1;              // bx and bx+8: same h, same XCD
  const int bh = bb * 16 + h;
  const int q0 = blockIdx.y * 16;
  const int cb = wave * 256;

  const unsigned short* qh  = qws  + (size_t)bh * SEQ * 64;
  const unsigned short* kh  = kws  + (size_t)bh * SEQ * 64;
  const unsigned short* vth = vtws + (size_t)bh * 64 * SEQ;
  float* out_o = out;
  float* out_w = out + (size_t)2 * N_HEAD * SEQ * 64;

  __shared__ float red[8][16];
  __shared__ unsigned short pbuf[8][16][40];   // C->A layout bounce
  __shared__ float obuf[8][16][68];            // cross-wave PV reduce

  // Q fragment (B-operand of swapped QK^T): lane -> Q[q=lrow][k=quad*8+j]
  bf16x8 aq[2];
  #pragma unroll
  for (int ks = 0; ks < 2; ++ks)
    aq[ks] = *(const bf16x8*)(qh + (size_t)(q0 + lrow) * 64 + ks * 32 + quad * 8);

  const unsigned short* kp = kh + (size_t)(cb + lrow) * 64 + quad * 8;
  const float* bp = bias + ((size_t)h * SEQ + q0 + lrow) * SEQ + cb + quad * 4;
  const int*   mp = mask + (size_t)(q0 + lrow) * SEQ + cb + quad * 4;

  const float L2E = 1.44269504f;
  us4 Sb[16];           // bf16 e-values: lane&15 = q-row, cols = cb+t*16+quad*4+r
  float rsum = 0.f;

  #pragma unroll
  for (int t = 0; t < 16; ++t) {
    bf16x8 k0f = *(const bf16x8*)(kp + t * 1024);        // k-rows, d 0..31
    bf16x8 k1f = *(const bf16x8*)(kp + t * 1024 + 32);   // d 32..63
    f32x4 c = (f32x4){0.f, 0.f, 0.f, 0.f};
    c = __builtin_amdgcn_mfma_f32_16x16x32_bf16(k0f, aq[0], c, 0, 0, 0);
    c = __builtin_amdgcn_mfma_f32_16x16x32_bf16(k1f, aq[1], c, 0, 0, 0);
    f32x4 bbv = *(const f32x4*)(bp + t * 16);
    i32x4 mmv = *(const i32x4*)(mp + t * 16);
    float e[4];
    #pragma unroll
    for (int r = 0; r < 4; ++r) {
      e[r] = (mmv[r] == 0) ? 0.f : exp2f((c[r] + bbv[r]) * L2E);
      rsum += e[r];
    }
    Sb[t] = (us4){ f2bf(e[0]), f2bf(e[1]), f2bf(e[2]), f2bf(e[3]) };
  }

  // row sum: quads of same q-row, then cross-wave via LDS
  rsum += __shfl_xor(rsum, 16);
  rsum += __shfl_xor(rsum, 32);
  if (lane < 16) red[wave][lrow] = rsum;
  __syncthreads();
  float tot = 0.f;
  #pragma unroll
  for (int w = 0; w < 8; ++w) tot += red[w][lrow];
  const float inv = 1.0f / tot;        // for the weights output (rows = lrow)

  f32x4 O[4];
  #pragma unroll
  for (int n = 0; n < 4; ++n) O[n] = (f32x4){0.f, 0.f, 0.f, 0.f};

  float* wbase = out_w + ((size_t)bh * SEQ + q0 + lrow) * SEQ + cb + quad * 4;
  const unsigned short* vp = vth + (size_t)lrow * SEQ + cb + quad * 8;

  // PV per 32-col window: bounce UNNORMALIZED bf16(e) through LDS (C->A),
  // write normalized weights (float4) from registers in the same pass.
  #pragma unroll
  for (int cc = 0; cc < 8; ++cc) {
    #pragma unroll
    for (int tt = 0; tt < 2; ++tt) {
      const int t = cc * 2 + tt;
      us4 u = Sb[t];
      *(us4*)&pbuf[wave][lrow][tt * 16 + quad * 4] = u;
      f32x4 wv = { b2f(u[0]) * inv, b2f(u[1]) * inv,
                   b2f(u[2]) * inv, b2f(u[3]) * inv };
      *(f32x4*)(wbase + t * 16) = wv;
    }
    asm volatile("s_waitcnt lgkmcnt(0)" ::: "memory");  // wave-internal LDS RAW
    bf16x8 aw = *(const bf16x8*)&pbuf[wave][lrow][quad * 8];
    #pragma unroll
    for (int n = 0; n < 4; ++n) {
      bf16x8 v8 = *(const bf16x8*)(vp + (size_t)n * 16 * SEQ + cc * 32);
      O[n] = __builtin_amdgcn_mfma_f32_16x16x32_bf16(aw, v8, O[n], 0, 0, 0);
    }
  }

  // cross-wave reduce of O (unnormalized); normalize by row-sum here.
  #pragma unroll
  for (int n = 0; n < 4; ++n)
    #pragma unroll
    for (int r = 0; r < 4; ++r)
      obuf[wave][quad * 4 + r][n * 16 + lrow] = O[n][r];
  __syncthreads();
  #pragma unroll
  for (int e = 0; e < 2; ++e) {
    int idx = e * 512 + tid;
    int row = idx >> 6, dd = idx & 63;
    float v = 0.f;
    #pragma unroll
    for (int w = 0; w < 8; ++w) v += obuf[w][row][dd];
    float totr = 0.f;
    #pragma unroll
    for (int w = 0; w < 8; ++w) totr += red[w][row];
    out_o[((size_t)bh * SEQ + q0 + row) * 64 + dd] = v * (1.0f / totr);
  }
}

extern "C" void kernel_launch(void* const* d_in, const int* in_sizes, int n_in,
                              void* d_out, int out_size, void* d_ws, size_t ws_size,
                              hipStream_t stream) {
  const float* x    = (const float*)d_in[0];
  const float* bias = (const float*)d_in[1];
  const int*   mask = (const int*)d_in[2];
  const float* wq   = (const float*)d_in[3];
  const float* bq   = (const float*)d_in[4];
  const float* wk   = (const float*)d_in[5];
  const float* bk   = (const float*)d_in[6];
  const float* wv   = (const float*)d_in[7];
  const float* bv   = (const float*)d_in[8];

  unsigned short* qws  = (unsigned short*)d_ws;           // 8 MB
  unsigned short* kws  = qws + (size_t)4194304;           // 8 MB
  unsigned short* vtws = kws + (size_t)4194304;           // 8 MB (V^T)
  float* out = (float*)d_out;

  // bf16 staging scratch (14 MB): prefer ws if it fits, else tail of d_out.
  // d_out tail is safe: conv/qkv read it strictly BEFORE attn2 overwrites
  // out_w (stream-ordered), and attn2 rewrites every byte afterwards.
  unsigned short* xb;
  if (ws_size >= (size_t)39845888) {
    xb = vtws + (size_t)4194304;
  } else {
    xb = (unsigned short*)((char*)d_out + ((size_t)out_size - (size_t)14 * 1024 * 1024));
  }
  unsigned short* wb = xb + (size_t)4194304;

  conv_bf16<<<dim3(3584), 256, 0, stream>>>(x, wq, wk, wv, xb, wb);
  qkv_gemm_bf16<<<dim3(32, 8, 3), 256, 0, stream>>>(xb, wb, bq, bk, bv,
                                                    qws, kws, vtws);
  // grid: x = swizzled bh (bias-sharing pairs 8 apart -> same XCD), y = strips
  attn2<<<dim3(32, 128), 512, 0, stream>>>(qws, kws, vtws, bias, mask, out);
}